// Round 1
// baseline (595.188 us; speedup 1.0000x reference)
//
#include <hip/hip_runtime.h>

// Advect: minmod-slope-limited upwind flux divergence along axis=1.
// Shapes: rho,v (16, 4100, 1024) f32 -> out (16, 4096, 1024) f32.
// Memory-bound streaming kernel: each thread owns 4 contiguous k (float4)
// and marches a 64-row j-chunk with a sliding register window, so every
// rho/v element is loaded once (+4-row halo per chunk) and out written once.

constexpr int NB    = 16;
constexpr int NJ    = 4100;
constexpr int NK    = 1024;
constexpr int NJO   = 4096;
constexpr int CHUNK = 64;   // output rows per thread; 1024 blocks -> 16 waves/CU

// half_slope = 0.5 * minmod(theta=2) — exact op order of the reference
__device__ __forceinline__ float hs_fn(float fm, float f0, float fp) {
    float s0 = 2.0f * (f0 - fm);
    float s1 = 0.5f * (fp - fm);
    float s2 = 2.0f * (fp - f0);
    float mn = fminf(fminf(s0, s1), s2);
    float mx = fmaxf(fmaxf(s0, s1), s2);
    float slope = (mn < 0.0f) ? fminf(mx, 0.0f) : mn;
    return 0.5f * slope;
}

__global__ __launch_bounds__(256, 4) void advect_kernel(
    const float* __restrict__ rho, const float* __restrict__ vel,
    float* __restrict__ out)
{
    const int b  = blockIdx.y;
    const int i0 = blockIdx.x * CHUNK;       // first output row of this chunk
    const int k0 = threadIdx.x * 4;          // 4 k's per thread (float4)

    const size_t inb  = (size_t)b * NJ  * NK + k0;
    const size_t outb = (size_t)b * NJO * NK + k0;

    const float4* rp = (const float4*)(rho + inb);
    const float4* vp = (const float4*)(vel + inb);
    const int js = NK / 4;                   // j-stride in float4 units

    // Sliding window state per component:
    //  fb=f[i+2], fc=f[i+3], vb=v[i+2], vc=v[i+3], hs2=hs[i+2], Gp=G(i)
    float fb[4], fc[4], vb[4], vc[4], hs2[4], Gp[4];

    { // prologue: rows i0..i0+3
        float4 r0 = rp[(size_t)(i0+0)*js], w0 = vp[(size_t)(i0+0)*js];
        float4 r1 = rp[(size_t)(i0+1)*js], w1 = vp[(size_t)(i0+1)*js];
        float4 r2 = rp[(size_t)(i0+2)*js], w2 = vp[(size_t)(i0+2)*js];
        float4 r3 = rp[(size_t)(i0+3)*js], w3 = vp[(size_t)(i0+3)*js];
        const float f0c[4] = {r0.x*w0.x, r0.y*w0.y, r0.z*w0.z, r0.w*w0.w};
        const float f1c[4] = {r1.x*w1.x, r1.y*w1.y, r1.z*w1.z, r1.w*w1.w};
        const float f2c[4] = {r2.x*w2.x, r2.y*w2.y, r2.z*w2.z, r2.w*w2.w};
        const float f3c[4] = {r3.x*w3.x, r3.y*w3.y, r3.z*w3.z, r3.w*w3.w};
        const float v1c[4] = {w1.x, w1.y, w1.z, w1.w};
        const float v2c[4] = {w2.x, w2.y, w2.z, w2.w};
        const float v3c[4] = {w3.x, w3.y, w3.z, w3.w};
        const bool interior = (i0 > 0);      // flux_plus[0] forced to 0
        #pragma unroll
        for (int c = 0; c < 4; ++c) {
            float h1 = hs_fn(f0c[c], f1c[c], f2c[c]);   // hs[i0+1]
            float h2 = hs_fn(f1c[c], f2c[c], f3c[c]);   // hs[i0+2]
            float minus = (v2c[c] < 0.0f) ? (f2c[c] - h2) : 0.0f;
            float plus  = (interior && v1c[c] > 0.0f) ? (f1c[c] + h1) : 0.0f;
            Gp[c] = minus + plus;                        // G(i0)
            fb[c] = f2c[c]; fc[c] = f3c[c];
            vb[c] = v2c[c]; vc[c] = v3c[c];
            hs2[c] = h2;
        }
    }

    #pragma unroll 4
    for (int t = 0; t < CHUNK; ++t) {
        const int i = i0 + t;
        const float4 rd4 = rp[(size_t)(i+4)*js];
        const float4 wd4 = vp[(size_t)(i+4)*js];
        const float rd[4] = {rd4.x, rd4.y, rd4.z, rd4.w};
        const float wd[4] = {wd4.x, wd4.y, wd4.z, wd4.w};
        const bool not_last = (i + 1) < NJO;             // flux_minus[-1] -> 0
        float o[4];
        #pragma unroll
        for (int c = 0; c < 4; ++c) {
            float fd = rd[c] * wd[c];                    // f[i+4]
            float h3 = hs_fn(fb[c], fc[c], fd);          // hs[i+3]
            float minus = (not_last && vc[c] < 0.0f) ? (fc[c] - h3) : 0.0f;
            float plus  = (vb[c] > 0.0f) ? (fb[c] + hs2[c]) : 0.0f;
            float G = minus + plus;                      // G(i+1)
            o[c] = Gp[c] - G;                            // out[i] = G(i)-G(i+1)
            Gp[c] = G;
            fb[c] = fc[c]; fc[c] = fd;
            vb[c] = vc[c]; vc[c] = wd[c];
            hs2[c] = h3;
        }
        *(float4*)(out + outb + (size_t)i * NK) = make_float4(o[0], o[1], o[2], o[3]);
    }
}

extern "C" void kernel_launch(void* const* d_in, const int* in_sizes, int n_in,
                              void* d_out, int out_size, void* d_ws, size_t ws_size,
                              hipStream_t stream) {
    const float* rho = (const float*)d_in[0];
    const float* vel = (const float*)d_in[1];
    float* out = (float*)d_out;
    (void)in_sizes; (void)n_in; (void)d_ws; (void)ws_size; (void)out_size;

    dim3 grid(NJO / CHUNK, NB);   // (64, 16) = 1024 blocks
    dim3 block(256);              // 256 threads x float4 = all 1024 k
    advect_kernel<<<grid, block, 0, stream>>>(rho, vel, out);
}